// Round 1
// baseline (8198.076 us; speedup 1.0000x reference)
//
#include <hip/hip_runtime.h>

#define N_NODES 100000
#define IN_CH 16
#define HIDDEN 32
#define NUM_HH 1000

// ---------------------------------------------------------------------------
// Edge scatter: agg[dst] += feat[src] (f32 atomics), optionally count degree.
// ---------------------------------------------------------------------------
template <int CH, bool COUNT>
__global__ __launch_bounds__(256) void edge_scatter(
    const int* __restrict__ src, const int* __restrict__ dst,
    const float* __restrict__ feat, float* __restrict__ agg,
    float* __restrict__ cnt, int n_edges) {
  int e = blockIdx.x * blockDim.x + threadIdx.x;
  if (e >= n_edges) return;
  int s = src[e];
  int d = dst[e];
  const float4* f4 = (const float4*)(feat + (size_t)s * CH);
  float4 v[CH / 4];
#pragma unroll
  for (int k = 0; k < CH / 4; ++k) v[k] = f4[k];
  if (COUNT) atomicAdd(cnt + d, 1.0f);
  float* a = agg + (size_t)d * CH;
#pragma unroll
  for (int k = 0; k < CH / 4; ++k) {
    atomicAdd(a + 4 * k + 0, v[k].x);
    atomicAdd(a + 4 * k + 1, v[k].y);
    atomicAdd(a + 4 * k + 2, v[k].z);
    atomicAdd(a + 4 * k + 3, v[k].w);
  }
}

// ---------------------------------------------------------------------------
// Node update: out[n] = relu((agg[n]/max(cnt,1)) @ w_l + b + feat[n] @ w_r)
// Weights staged in LDS, read as float4 broadcasts (uniform addr, no conflict)
// ---------------------------------------------------------------------------
template <int CH>
__global__ __launch_bounds__(256) void node_update(
    const float* __restrict__ feat, const float* __restrict__ agg,
    const float* __restrict__ cnt, const float* __restrict__ w_l,
    const float* __restrict__ w_r, const float* __restrict__ b,
    float* __restrict__ out) {
  __shared__ float wl[CH * HIDDEN];
  __shared__ float wr[CH * HIDDEN];
  __shared__ float bs[HIDDEN];
  for (int i = threadIdx.x; i < CH * HIDDEN; i += blockDim.x) {
    wl[i] = w_l[i];
    wr[i] = w_r[i];
  }
  if (threadIdx.x < HIDDEN) bs[threadIdx.x] = b[threadIdx.x];
  __syncthreads();

  int n = blockIdx.x * blockDim.x + threadIdx.x;
  if (n >= N_NODES) return;

  float inv = 1.0f / fmaxf(cnt[n], 1.0f);
  float m[CH], xv[CH];
  const float4* a4 = (const float4*)(agg + (size_t)n * CH);
  const float4* x4 = (const float4*)(feat + (size_t)n * CH);
#pragma unroll
  for (int k = 0; k < CH / 4; ++k) {
    float4 av = a4[k];
    float4 xx = x4[k];
    m[4 * k + 0] = av.x * inv;
    m[4 * k + 1] = av.y * inv;
    m[4 * k + 2] = av.z * inv;
    m[4 * k + 3] = av.w * inv;
    xv[4 * k + 0] = xx.x;
    xv[4 * k + 1] = xx.y;
    xv[4 * k + 2] = xx.z;
    xv[4 * k + 3] = xx.w;
  }

  float o[HIDDEN];
#pragma unroll
  for (int j = 0; j < HIDDEN; ++j) o[j] = bs[j];

  const float4* wl4 = (const float4*)wl;
  const float4* wr4 = (const float4*)wr;
#pragma unroll
  for (int k = 0; k < CH; ++k) {
#pragma unroll
    for (int j4 = 0; j4 < HIDDEN / 4; ++j4) {
      float4 a = wl4[k * (HIDDEN / 4) + j4];
      float4 r = wr4[k * (HIDDEN / 4) + j4];
      o[4 * j4 + 0] = fmaf(m[k], a.x, fmaf(xv[k], r.x, o[4 * j4 + 0]));
      o[4 * j4 + 1] = fmaf(m[k], a.y, fmaf(xv[k], r.y, o[4 * j4 + 1]));
      o[4 * j4 + 2] = fmaf(m[k], a.z, fmaf(xv[k], r.z, o[4 * j4 + 2]));
      o[4 * j4 + 3] = fmaf(m[k], a.w, fmaf(xv[k], r.w, o[4 * j4 + 3]));
    }
  }

  float4* o4 = (float4*)(out + (size_t)n * HIDDEN);
#pragma unroll
  for (int j4 = 0; j4 < HIDDEN / 4; ++j4) {
    float4 v;
    v.x = fmaxf(o[4 * j4 + 0], 0.0f);
    v.y = fmaxf(o[4 * j4 + 1], 0.0f);
    v.z = fmaxf(o[4 * j4 + 2], 0.0f);
    v.w = fmaxf(o[4 * j4 + 3], 0.0f);
    o4[j4] = v;
  }
}

// ---------------------------------------------------------------------------
// FC head: out[N,1000] = h[N,32] @ fc_w[32,1000] + fc_b
// Block: 128-node tile in LDS; each thread owns one output column j
// (fc_w column in registers), loops nodes; writes coalesced across j.
// ---------------------------------------------------------------------------
#define FC_BN 128
__global__ __launch_bounds__(256) void fc_kernel(
    const float* __restrict__ h, const float* __restrict__ fcw,
    const float* __restrict__ fcb, float* __restrict__ out) {
  __shared__ float hs[FC_BN * HIDDEN];
  int base = blockIdx.x * FC_BN;
  int nvalid = min(FC_BN, N_NODES - base);

  int cnt4 = nvalid * HIDDEN / 4;
  const float4* s4 = (const float4*)(h + (size_t)base * HIDDEN);
  for (int i = threadIdx.x; i < cnt4; i += 256) ((float4*)hs)[i] = s4[i];
  __syncthreads();

#pragma unroll
  for (int c = 0; c < 4; ++c) {
    int j = c * 256 + threadIdx.x;
    if (j < NUM_HH) {
      float w[HIDDEN];
#pragma unroll
      for (int k = 0; k < HIDDEN; ++k) w[k] = fcw[k * NUM_HH + j];
      float bias = fcb[j];
      int n = 0;
      for (; n + 2 <= nvalid; n += 2) {
        float a0 = bias, a1 = bias;
#pragma unroll
        for (int k = 0; k < HIDDEN; ++k) {
          a0 = fmaf(hs[n * HIDDEN + k], w[k], a0);
          a1 = fmaf(hs[(n + 1) * HIDDEN + k], w[k], a1);
        }
        out[(size_t)(base + n) * NUM_HH + j] = a0;
        out[(size_t)(base + n + 1) * NUM_HH + j] = a1;
      }
      for (; n < nvalid; ++n) {
        float a0 = bias;
#pragma unroll
        for (int k = 0; k < HIDDEN; ++k)
          a0 = fmaf(hs[n * HIDDEN + k], w[k], a0);
        out[(size_t)(base + n) * NUM_HH + j] = a0;
      }
    }
  }
}

extern "C" void kernel_launch(void* const* d_in, const int* in_sizes, int n_in,
                              void* d_out, int out_size, void* d_ws,
                              size_t ws_size, hipStream_t stream) {
  const float* x = (const float*)d_in[0];
  const int* edge = (const int*)d_in[1];
  const float* w1_l = (const float*)d_in[2];
  const float* w1_r = (const float*)d_in[3];
  const float* b1 = (const float*)d_in[4];
  const float* w2_l = (const float*)d_in[5];
  const float* w2_r = (const float*)d_in[6];
  const float* b2 = (const float*)d_in[7];
  const float* fc_w = (const float*)d_in[8];
  const float* fc_b = (const float*)d_in[9];
  float* out = (float*)d_out;

  const int n_edges = in_sizes[1] / 2;
  const int* src = edge;
  const int* dst = edge + n_edges;

  // Workspace layout (all f32): cnt[N] | agg[N*32] | h[N*32]  = 26 MB
  float* cnt = (float*)d_ws;
  float* agg = cnt + N_NODES;
  float* h = agg + (size_t)N_NODES * HIDDEN;

  const int EB = 256;
  const int egrid = (n_edges + EB - 1) / EB;
  const int ngrid = (N_NODES + 255) / 256;
  const int fgrid = (N_NODES + FC_BN - 1) / FC_BN;

  // Layer 1: zero cnt+agg (contiguous), scatter x, node update -> h
  hipMemsetAsync(cnt, 0, (size_t)N_NODES * (1 + HIDDEN) * sizeof(float),
                 stream);
  edge_scatter<IN_CH, true><<<egrid, EB, 0, stream>>>(src, dst, x, agg, cnt,
                                                      n_edges);
  node_update<IN_CH><<<ngrid, 256, 0, stream>>>(x, agg, cnt, w1_l, w1_r, b1,
                                                h);

  // Layer 2: zero agg, scatter h, node update in place over h
  hipMemsetAsync(agg, 0, (size_t)N_NODES * HIDDEN * sizeof(float), stream);
  edge_scatter<HIDDEN, false><<<egrid, EB, 0, stream>>>(src, dst, h, agg, cnt,
                                                        n_edges);
  node_update<HIDDEN><<<ngrid, 256, 0, stream>>>(h, agg, cnt, w2_l, w2_r, b2,
                                                 h);

  // FC head
  fc_kernel<<<fgrid, 256, 0, stream>>>(h, fc_w, fc_b, out);
}

// Round 2
// 750.663 us; speedup vs baseline: 10.9211x; 10.9211x over previous
//
#include <hip/hip_runtime.h>

#define N_NODES 100000
#define IN_CH 16
#define HIDDEN 32
#define NUM_HH 1000
#define SCAN_B 1024
#define NBLK ((N_NODES + SCAN_B - 1) / SCAN_B)  // 98

// ---------------------------------------------------------------------------
// CSR build: degree histogram -> exclusive scan -> bucket placement
// ---------------------------------------------------------------------------
__global__ __launch_bounds__(256) void hist_kernel(const int* __restrict__ dst,
                                                   int* __restrict__ deg,
                                                   int n_edges) {
  int e = blockIdx.x * blockDim.x + threadIdx.x;
  if (e < n_edges) atomicAdd(deg + dst[e], 1);
}

// exclusive scan of deg within each 1024-block -> row_ptr; block sums -> partials
__global__ __launch_bounds__(SCAN_B) void scan_local(
    const int* __restrict__ deg, int* __restrict__ row_ptr,
    int* __restrict__ partials) {
  __shared__ int tmp[SCAN_B];
  int i = blockIdx.x * SCAN_B + threadIdx.x;
  int v = (i < N_NODES) ? deg[i] : 0;
  tmp[threadIdx.x] = v;
  __syncthreads();
  for (int off = 1; off < SCAN_B; off <<= 1) {
    int t = (threadIdx.x >= off) ? tmp[threadIdx.x - off] : 0;
    __syncthreads();
    tmp[threadIdx.x] += t;
    __syncthreads();
  }
  if (i < N_NODES) row_ptr[i] = tmp[threadIdx.x] - v;  // exclusive
  if (threadIdx.x == SCAN_B - 1) partials[blockIdx.x] = tmp[threadIdx.x];
}

__global__ __launch_bounds__(128) void scan_partials(int* __restrict__ partials) {
  __shared__ int tmp[128];
  int v = (threadIdx.x < NBLK) ? partials[threadIdx.x] : 0;
  tmp[threadIdx.x] = v;
  __syncthreads();
  for (int off = 1; off < 128; off <<= 1) {
    int t = (threadIdx.x >= off) ? tmp[threadIdx.x - off] : 0;
    __syncthreads();
    tmp[threadIdx.x] += t;
    __syncthreads();
  }
  if (threadIdx.x < NBLK) partials[threadIdx.x] = tmp[threadIdx.x] - v;  // exclusive
}

__global__ __launch_bounds__(SCAN_B) void scan_add(int* __restrict__ row_ptr,
                                                   const int* __restrict__ partials,
                                                   int* __restrict__ cursor,
                                                   int n_edges) {
  int i = blockIdx.x * SCAN_B + threadIdx.x;
  if (i < N_NODES) {
    int v = row_ptr[i] + partials[blockIdx.x];
    row_ptr[i] = v;
    cursor[i] = v;
  }
  if (i == 0) row_ptr[N_NODES] = n_edges;
}

__global__ __launch_bounds__(256) void place_kernel(const int* __restrict__ src,
                                                    const int* __restrict__ dst,
                                                    int* __restrict__ cursor,
                                                    int* __restrict__ adj,
                                                    int n_edges) {
  int e = blockIdx.x * blockDim.x + threadIdx.x;
  if (e >= n_edges) return;
  int pos = atomicAdd(cursor + dst[e], 1);
  adj[pos] = src[e];
}

// ---------------------------------------------------------------------------
// Fused SAGE layer: one wave per node.
// Phase 1: lanes gather x[adj[i]] quads, shfl_xor butterfly -> mean in LDS.
// Phase 2: in-wave GEMV: lanes 0-31 own output col j (halves split over k),
//          out = relu(mean@w_l + x@w_r + b).
// ---------------------------------------------------------------------------
template <int CH>
__global__ __launch_bounds__(256) void sage_fused(
    const float* __restrict__ feat, const int* __restrict__ row_ptr,
    const int* __restrict__ adj, const float* __restrict__ w_l,
    const float* __restrict__ w_r, const float* __restrict__ b,
    float* __restrict__ out) {
  constexpr int Q = CH / 4;    // float4 quads per node row
  constexpr int EPW = 64 / Q;  // edges gathered per wave iteration
  __shared__ float wl[CH * HIDDEN];
  __shared__ float wr[CH * HIDDEN];
  __shared__ float bs[HIDDEN];
  __shared__ float mean_s[4][CH];
  __shared__ float xs[4][CH];
  for (int i = threadIdx.x; i < CH * HIDDEN; i += 256) {
    wl[i] = w_l[i];
    wr[i] = w_r[i];
  }
  if (threadIdx.x < HIDDEN) bs[threadIdx.x] = b[threadIdx.x];

  const int wave = threadIdx.x >> 6;
  const int lane = threadIdx.x & 63;
  const int n = blockIdx.x * 4 + wave;  // grid sized so n < N_NODES always

  const int s = row_ptr[n];
  const int e = row_ptr[n + 1];
  const int q = lane % Q;
  const int esub = lane / Q;

  float4 acc = {0.f, 0.f, 0.f, 0.f};
  for (int i = s + esub; i < e; i += EPW) {
    const float4 v = ((const float4*)(feat + (size_t)adj[i] * CH))[q];
    acc.x += v.x;
    acc.y += v.y;
    acc.z += v.z;
    acc.w += v.w;
  }
#pragma unroll
  for (int m = Q; m < 64; m <<= 1) {
    acc.x += __shfl_xor(acc.x, m, 64);
    acc.y += __shfl_xor(acc.y, m, 64);
    acc.z += __shfl_xor(acc.z, m, 64);
    acc.w += __shfl_xor(acc.w, m, 64);
  }
  const float inv = 1.0f / fmaxf((float)(e - s), 1.0f);
  if (esub == 0) {  // lane == q
    mean_s[wave][4 * q + 0] = acc.x * inv;
    mean_s[wave][4 * q + 1] = acc.y * inv;
    mean_s[wave][4 * q + 2] = acc.z * inv;
    mean_s[wave][4 * q + 3] = acc.w * inv;
    const float4 xv = ((const float4*)(feat + (size_t)n * CH))[q];
    xs[wave][4 * q + 0] = xv.x;
    xs[wave][4 * q + 1] = xv.y;
    xs[wave][4 * q + 2] = xv.z;
    xs[wave][4 * q + 3] = xv.w;
  }
  __syncthreads();

  const int j = lane & 31;
  const int p = lane >> 5;  // half-wave splits the k range
  float o = 0.f;
#pragma unroll
  for (int k = p * (CH / 2); k < (p + 1) * (CH / 2); ++k)
    o = fmaf(mean_s[wave][k], wl[k * HIDDEN + j],
             fmaf(xs[wave][k], wr[k * HIDDEN + j], o));
  o += __shfl_xor(o, 32, 64);
  if (p == 0) out[(size_t)n * HIDDEN + j] = fmaxf(o + bs[j], 0.f);
}

// ---------------------------------------------------------------------------
// FC head: out[N,1000] = h[N,32] @ fc_w[32,1000] + fc_b
// ---------------------------------------------------------------------------
#define FC_BN 128
__global__ __launch_bounds__(256) void fc_kernel(
    const float* __restrict__ h, const float* __restrict__ fcw,
    const float* __restrict__ fcb, float* __restrict__ out) {
  __shared__ float hs[FC_BN * HIDDEN];
  int base = blockIdx.x * FC_BN;
  int nvalid = min(FC_BN, N_NODES - base);

  int cnt4 = nvalid * HIDDEN / 4;
  const float4* s4 = (const float4*)(h + (size_t)base * HIDDEN);
  for (int i = threadIdx.x; i < cnt4; i += 256) ((float4*)hs)[i] = s4[i];
  __syncthreads();

#pragma unroll
  for (int c = 0; c < 4; ++c) {
    int j = c * 256 + threadIdx.x;
    if (j < NUM_HH) {
      float w[HIDDEN];
#pragma unroll
      for (int k = 0; k < HIDDEN; ++k) w[k] = fcw[k * NUM_HH + j];
      float bias = fcb[j];
      int n = 0;
      for (; n + 2 <= nvalid; n += 2) {
        float a0 = bias, a1 = bias;
#pragma unroll
        for (int k = 0; k < HIDDEN; ++k) {
          a0 = fmaf(hs[n * HIDDEN + k], w[k], a0);
          a1 = fmaf(hs[(n + 1) * HIDDEN + k], w[k], a1);
        }
        out[(size_t)(base + n) * NUM_HH + j] = a0;
        out[(size_t)(base + n + 1) * NUM_HH + j] = a1;
      }
      for (; n < nvalid; ++n) {
        float a0 = bias;
#pragma unroll
        for (int k = 0; k < HIDDEN; ++k)
          a0 = fmaf(hs[n * HIDDEN + k], w[k], a0);
        out[(size_t)(base + n) * NUM_HH + j] = a0;
      }
    }
  }
}

extern "C" void kernel_launch(void* const* d_in, const int* in_sizes, int n_in,
                              void* d_out, int out_size, void* d_ws,
                              size_t ws_size, hipStream_t stream) {
  const float* x = (const float*)d_in[0];
  const int* edge = (const int*)d_in[1];
  const float* w1_l = (const float*)d_in[2];
  const float* w1_r = (const float*)d_in[3];
  const float* b1 = (const float*)d_in[4];
  const float* w2_l = (const float*)d_in[5];
  const float* w2_r = (const float*)d_in[6];
  const float* b2 = (const float*)d_in[7];
  const float* fc_w = (const float*)d_in[8];
  const float* fc_b = (const float*)d_in[9];
  float* out = (float*)d_out;

  const int n_edges = in_sizes[1] / 2;
  const int* src = edge;
  const int* dst = edge + n_edges;

  // Workspace layout. 16B-aligned buffers first:
  //   adj[E] | h1[N*32] | h2[N*32] | deg[N] | row_ptr[N+1] | cursor[N] | partials[128]
  int* adj = (int*)d_ws;
  float* h1 = (float*)(adj + n_edges);
  float* h2 = h1 + (size_t)N_NODES * HIDDEN;
  int* deg = (int*)(h2 + (size_t)N_NODES * HIDDEN);
  int* row_ptr = deg + N_NODES;
  int* cursor = row_ptr + N_NODES + 1;
  int* partials = cursor + N_NODES;

  const int EB = 256;
  const int egrid = (n_edges + EB - 1) / EB;
  const int sgrid = N_NODES / 4;  // 25000, exact: 4 nodes (waves) per block
  const int fgrid = (N_NODES + FC_BN - 1) / FC_BN;

  // ---- CSR build (shared by both layers) ----
  hipMemsetAsync(deg, 0, (size_t)N_NODES * sizeof(int), stream);
  hist_kernel<<<egrid, EB, 0, stream>>>(dst, deg, n_edges);
  scan_local<<<NBLK, SCAN_B, 0, stream>>>(deg, row_ptr, partials);
  scan_partials<<<1, 128, 0, stream>>>(partials);
  scan_add<<<NBLK, SCAN_B, 0, stream>>>(row_ptr, partials, cursor, n_edges);
  place_kernel<<<egrid, EB, 0, stream>>>(src, dst, cursor, adj, n_edges);

  // ---- Layer 1 (CH=16): gather+update fused ----
  sage_fused<IN_CH><<<sgrid, 256, 0, stream>>>(x, row_ptr, adj, w1_l, w1_r, b1,
                                               h1);
  // ---- Layer 2 (CH=32) ----
  sage_fused<HIDDEN><<<sgrid, 256, 0, stream>>>(h1, row_ptr, adj, w2_l, w2_r,
                                                b2, h2);
  // ---- FC head ----
  fc_kernel<<<fgrid, 256, 0, stream>>>(h2, fc_w, fc_b, out);
}